// Round 7
// baseline (1267.148 us; speedup 1.0000x reference)
//
#include <hip/hip_runtime.h>
#include <hip/hip_bf16.h>
#include <math.h>

#define BDIM 2
#define SDIM 2048
#define HDIM 16
#define HD 128
#define HID 2048
#define FFD 8192
#define NTOK (BDIM*SDIM)
#define QKVW (3*HID)

typedef __hip_bfloat16 bf16;
typedef __attribute__((ext_vector_type(8))) short short8;
typedef __attribute__((ext_vector_type(4))) short short4_;
typedef __attribute__((ext_vector_type(4))) float floatx4;

__device__ inline short bfbits(float f) {
  bf16 h = __float2bfloat16(f);
  short s;
  __builtin_memcpy(&s, &h, 2);
  return s;
}

// Abramowitz-Stegun 7.1.26 erf approximation, |err| <= 1.5e-7.
__device__ inline float fast_erf(float x) {
  float ax = fabsf(x);
  float t = __builtin_amdgcn_rcpf(1.0f + 0.3275911f * ax);
  float p = t * (0.254829592f + t * (-0.284496736f + t * (1.421413741f
          + t * (-1.453152027f + t * 1.061405429f))));
  float e = __expf(-ax * ax);
  float r = 1.0f - p * e;
  return copysignf(r, x);
}

// ---------------- weight transpose + f32->bf16 convert ----------------
__global__ __launch_bounds__(256) void transpose_cvt(
    const float* __restrict__ W, bf16* __restrict__ Wt, int K, int N)
{
  __shared__ float tile[32][33];
  int n0 = blockIdx.x * 32, k0 = blockIdx.y * 32;
  int tx = threadIdx.x, ty = threadIdx.y;  // 32 x 8
  #pragma unroll
  for (int r = ty; r < 32; r += 8)
    tile[r][tx] = W[(size_t)(k0 + r) * N + n0 + tx];
  __syncthreads();
  #pragma unroll
  for (int r = ty; r < 32; r += 8)
    Wt[(size_t)(n0 + r) * K + k0 + tx] = __float2bfloat16(tile[tx][r]);
}

// ---------------- fused LayerNorm (both LN1 and LN2) ----------------
__global__ __launch_bounds__(256) void ln_both(
    const float* __restrict__ x,
    const float* __restrict__ g1, const float* __restrict__ b1,
    const float* __restrict__ g2, const float* __restrict__ b2,
    bf16* __restrict__ o1, bf16* __restrict__ o2)
{
  int row = blockIdx.x;
  int tid = threadIdx.x;
  const float4* xr = (const float4*)(x + (size_t)row * HID);
  float4 va = xr[tid], vb = xr[tid + 256];
  float s = va.x + va.y + va.z + va.w + vb.x + vb.y + vb.z + vb.w;
  float q = va.x*va.x + va.y*va.y + va.z*va.z + va.w*va.w
          + vb.x*vb.x + vb.y*vb.y + vb.z*vb.z + vb.w*vb.w;
  #pragma unroll
  for (int off = 1; off < 64; off <<= 1) {
    s += __shfl_xor(s, off);
    q += __shfl_xor(q, off);
  }
  __shared__ float red[8];
  int wave = tid >> 6;
  if ((tid & 63) == 0) { red[wave] = s; red[4 + wave] = q; }
  __syncthreads();
  s = red[0] + red[1] + red[2] + red[3];
  q = red[4] + red[5] + red[6] + red[7];
  float mu = s * (1.0f / HID);
  float var = q * (1.0f / HID) - mu * mu;
  float rs = rsqrtf(var + 1e-5f);

  const float4* g1v = (const float4*)g1; const float4* b1v = (const float4*)b1;
  const float4* g2v = (const float4*)g2; const float4* b2v = (const float4*)b2;
  short4_* o1v = (short4_*)(o1 + (size_t)row * HID);
  short4_* o2v = (short4_*)(o2 + (size_t)row * HID);
  #pragma unroll
  for (int p = 0; p < 2; ++p) {
    int e = tid + p * 256;
    float4 xv = (p == 0) ? va : vb;
    float4 gv = g1v[e], bv = b1v[e];
    short4_ pk;
    pk[0] = bfbits((xv.x - mu) * rs * gv.x + bv.x);
    pk[1] = bfbits((xv.y - mu) * rs * gv.y + bv.y);
    pk[2] = bfbits((xv.z - mu) * rs * gv.z + bv.z);
    pk[3] = bfbits((xv.w - mu) * rs * gv.w + bv.w);
    o1v[e] = pk;
    gv = g2v[e]; bv = b2v[e];
    pk[0] = bfbits((xv.x - mu) * rs * gv.x + bv.x);
    pk[1] = bfbits((xv.y - mu) * rs * gv.y + bv.y);
    pk[2] = bfbits((xv.z - mu) * rs * gv.z + bv.z);
    pk[3] = bfbits((xv.w - mu) * rs * gv.w + bv.w);
    o2v[e] = pk;
  }
}

// ---------------- bf16 GEMM: BM x 256 tile, BK=64, 2-phase simple ----------
// r5/r6-verified minimum-T3 recipe (m230): stage-next -> compute-current ->
// ONE __syncthreads per K-tile; no asm pins. XOR chunk swizzle both-sides.
// EPI 1: bf16 out = gelu(acc + bias)   (fast_erf)
// EPI 2: f32 out = acc + bias + (f32)r1b + r2
// EPI 3: bf16 out = acc + bias
template<int EPI, int BM>
__global__ __launch_bounds__(512, 2) void gemm2p(
    const bf16* __restrict__ A, const bf16* __restrict__ Bt,
    const float* __restrict__ bias,
    float* __restrict__ Cf, bf16* __restrict__ Cb,
    const bf16* __restrict__ r1b, const float* __restrict__ r2,
    int M, int N, int K)
{
  constexpr int NI = BM / 32;   // acc row-frags per wave (4 or 8)
  __shared__ bf16 SA[2][BM * 64];
  __shared__ bf16 SB[2][256 * 64];
  const int tid = threadIdx.x;
  const int wave = tid >> 6, lane = tid & 63;
  const int quad = lane >> 4, l16 = lane & 15;
  const int wr = wave >> 2, wc = wave & 3;
  const int n0 = blockIdx.x * 256, m0 = blockIdx.y * BM;

  const int stg_r = tid >> 3;
  const int stg_c = ((tid & 7) ^ ((tid >> 3) & 7)) << 3;  // element offset
  const bf16* stgA = A + (size_t)(m0 + stg_r) * K + stg_c;
  const bf16* stgB = Bt + (size_t)(n0 + stg_r) * K + stg_c;

  floatx4 acc[NI][4];
  #pragma unroll
  for (int i = 0; i < NI; ++i)
    #pragma unroll
    for (int j = 0; j < 4; ++j) acc[i][j] = (floatx4)0.0f;

  const int KT = K >> 6;

#define STAGE_2P(KT1, BUF) {                                                   \
  const bf16* ga_ = stgA + (size_t)(KT1) * 64;                                 \
  const bf16* gb_ = stgB + (size_t)(KT1) * 64;                                 \
  _Pragma("unroll")                                                            \
  for (int s_ = 0; s_ < BM / 64; ++s_)                                         \
    __builtin_amdgcn_global_load_lds(                                          \
        (const __attribute__((address_space(1))) void*)(ga_ + (size_t)s_ * 64 * K), \
        (__attribute__((address_space(3))) void*)&SA[BUF][s_ * 4096 + wave * 512], 16, 0, 0); \
  _Pragma("unroll")                                                            \
  for (int s_ = 0; s_ < 4; ++s_)                                               \
    __builtin_amdgcn_global_load_lds(                                          \
        (const __attribute__((address_space(1))) void*)(gb_ + (size_t)s_ * 64 * K), \
        (__attribute__((address_space(3))) void*)&SB[BUF][s_ * 4096 + wave * 512], 16, 0, 0); }

  STAGE_2P(0, 0);
  __syncthreads();

  for (int kt = 0; kt < KT; ++kt) {
    const int cur = kt & 1;
    if (kt + 1 < KT) STAGE_2P(kt + 1, cur ^ 1);
    const bf16* as_ = &SA[cur][0];
    const bf16* bs_ = &SB[cur][0];
    #pragma unroll
    for (int kc = 0; kc < 2; ++kc) {
      const int csw = (((kc * 4 + quad) ^ (l16 & 7)) << 3);
      short8 av[NI], bv[4];
      #pragma unroll
      for (int i = 0; i < NI; ++i)
        av[i] = *(const short8*)&as_[(wr * (BM / 2) + i * 16 + l16) * 64 + csw];
      #pragma unroll
      for (int j = 0; j < 4; ++j)
        bv[j] = *(const short8*)&bs_[(wc * 64 + j * 16 + l16) * 64 + csw];
      #pragma unroll
      for (int i = 0; i < NI; ++i)
        #pragma unroll
        for (int j = 0; j < 4; ++j)
          acc[i][j] = __builtin_amdgcn_mfma_f32_16x16x32_bf16(av[i], bv[j], acc[i][j], 0, 0, 0);
    }
    __syncthreads();
  }
#undef STAGE_2P

  #pragma unroll
  for (int i = 0; i < NI; ++i) {
    #pragma unroll
    for (int j = 0; j < 4; ++j) {
      int col = n0 + wc * 64 + j * 16 + l16;
      float bsv = bias[col];
      #pragma unroll
      for (int r = 0; r < 4; ++r) {
        int row = m0 + wr * (BM / 2) + i * 16 + quad * 4 + r;
        size_t idx = (size_t)row * N + col;
        float v = acc[i][j][r] + bsv;
        if (EPI == 1) {
          v = 0.5f * v * (1.0f + fast_erf(v * 0.70710678118654752f));
          Cb[idx] = __float2bfloat16(v);
        } else if (EPI == 2) {
          Cf[idx] = v + __bfloat162float(r1b[idx]) + r2[idx];
        } else {
          Cb[idx] = __float2bfloat16(v);
        }
      }
    }
  }
}

// ---------------- RoPE in-place + Q pre-scale + V transpose ----------------
__global__ __launch_bounds__(256) void rope_vt(
    bf16* __restrict__ qkv, bf16* __restrict__ vT)
{
  int bh = blockIdx.x, s0 = blockIdx.y * 32;
  int b = bh >> 4, h = bh & 15;
  int tid = threadIdx.x;
  __shared__ bf16 vs[32][136];
  const float qsc = 0.12751740f;  // (1/sqrt(128)) * log2(e)

  for (int idx = tid; idx < 512; idx += 256) {
    int sl = idx >> 4, d = idx & 15;
    int s = s0 + sl;
    bf16* base = qkv + (size_t)(b * SDIM + s) * QKVW + h * 384;
    float fr = (float)s * expf(-(float)d * 0.5756462732485114f); // ln(10000)/16
    float c = cosf(fr), sn = sinf(fr);
    float q1 = __bfloat162float(base[d]);
    float q2 = __bfloat162float(base[d + 16]);
    float k1 = __bfloat162float(base[128 + d]);
    float k2 = __bfloat162float(base[128 + d + 16]);
    base[d]        = __float2bfloat16(qsc * (q1 * c - q2 * sn));
    base[d + 16]   = __float2bfloat16(qsc * (q2 * c + q1 * sn));
    base[128 + d]      = __float2bfloat16(k1 * c - k2 * sn);
    base[128 + d + 16] = __float2bfloat16(k2 * c + k1 * sn);
  }
  for (int idx = tid; idx < 32 * 96; idx += 256) {
    int sl = idx / 96, d = 32 + idx % 96;
    bf16* base = qkv + (size_t)(b * SDIM + s0 + sl) * QKVW + h * 384;
    base[d] = __float2bfloat16(qsc * __bfloat162float(base[d]));
  }

  for (int idx = tid; idx < 32 * 128; idx += 256) {
    int sl = idx >> 7, d = idx & 127;
    vs[sl][d] = qkv[(size_t)(b * SDIM + s0 + sl) * QKVW + h * 384 + 256 + d];
  }
  __syncthreads();
  for (int idx = tid; idx < 32 * 128; idx += 256) {
    int d = idx >> 5, sl = idx & 31;
    vT[((size_t)bh * HD + d) * SDIM + s0 + sl] = vs[sl][d];
  }
}

// ---------------- flash attention v4: one q-tile per wave -----------------
// r6 PMC: MfmaUtil 6.4%, Occupancy 11%, VGPR 188 (2 waves/SIMD) -> latency
// bound. v4: each wave owns ONE 16-row q-tile (state ~halves), heavy-first
// tile mapping (t = 127 - (4*blockIdx.y + wave)) for tail balance, and
// __launch_bounds__(256,3) caps VGPR at 170 -> 3 waves/SIMD (+50% TLP).
// Same-bh blocks still share an XCD (flat%8 = bh%8) -> K/V stay L2-hot.
// Math (mask rule, Ps layout, exp2-domain softmax with pre-scaled Q) is
// identical to the verified v3 macros.
#define LOAD_K(KB, K0) { \
  int krow_ = (K0); \
  _Pragma("unroll") for (int nh_ = 0; nh_ < 2; ++nh_) \
    _Pragma("unroll") for (int c_ = 0; c_ < 4; ++c_) \
      KB[nh_*4+c_] = *(const short8*)&Kb[(size_t)(krow_ + nh_*16 + l16) * QKVW + c_*32 + quad*8]; }

#define SOFTMAX1(S0, S1, K0, DOMASK) { \
  if (DOMASK) { \
    _Pragma("unroll") for (int r_ = 0; r_ < 4; ++r_) { \
      int row_ = q0 + quad*4 + r_; \
      S0[r_] = ((K0) + l16 <= row_) ? S0[r_] : -1e30f; \
      S1[r_] = ((K0) + 16 + l16 <= row_) ? S1[r_] : -1e30f; } } \
  _Pragma("unroll") for (int r_ = 0; r_ < 4; ++r_) { \
    float mx_ = fmaxf(S0[r_], S1[r_]); \
    mx_ = fmaxf(mx_, __shfl_xor(mx_, 1)); \
    mx_ = fmaxf(mx_, __shfl_xor(mx_, 2)); \
    mx_ = fmaxf(mx_, __shfl_xor(mx_, 4)); \
    mx_ = fmaxf(mx_, __shfl_xor(mx_, 8)); \
    float mnew_ = fmaxf(m[r_], mx_); \
    float alpha_ = __builtin_amdgcn_exp2f(m[r_] - mnew_); \
    m[r_] = mnew_; \
    S0[r_] = __builtin_amdgcn_exp2f(S0[r_] - mnew_); \
    S1[r_] = __builtin_amdgcn_exp2f(S1[r_] - mnew_); \
    float sm_ = S0[r_] + S1[r_]; \
    sm_ += __shfl_xor(sm_, 1); sm_ += __shfl_xor(sm_, 2); \
    sm_ += __shfl_xor(sm_, 4); sm_ += __shfl_xor(sm_, 8); \
    l[r_] = l[r_] * alpha_ + sm_; \
    _Pragma("unroll") for (int d_ = 0; d_ < 8; ++d_) o[d_][r_] *= alpha_; \
    Ps[wave][quad*4 + r_][l16]      = __float2bfloat16(S0[r_]); \
    Ps[wave][quad*4 + r_][16 + l16] = __float2bfloat16(S1[r_]); } }

#define FLASH_ITER1(IT, KC, KN) { \
  const int k0_ = (IT) * 32; \
  const int k0n_ = ((IT) + 1 < nk) ? k0_ + 32 : 0; \
  LOAD_K(KN, k0n_); \
  short8 vbuf_[8]; \
  _Pragma("unroll") for (int d_ = 0; d_ < 8; ++d_) \
    vbuf_[d_] = *(const short8*)&Vb[(size_t)(d_*16 + l16) * SDIM + k0_ + quad*8]; \
  floatx4 sc_[2]; sc_[0] = (floatx4)0.0f; sc_[1] = (floatx4)0.0f; \
  _Pragma("unroll") for (int c_ = 0; c_ < 4; ++c_) { \
    sc_[0] = __builtin_amdgcn_mfma_f32_16x16x32_bf16(aq[c_], KC[c_],   sc_[0], 0,0,0); \
    sc_[1] = __builtin_amdgcn_mfma_f32_16x16x32_bf16(aq[c_], KC[4+c_], sc_[1], 0,0,0); } \
  SOFTMAX1(sc_[0], sc_[1], k0_, (k0_ + 32 >= kmax)); \
  short8 pf_ = *(const short8*)&Ps[wave][l16][quad*8]; \
  _Pragma("unroll") for (int d_ = 0; d_ < 8; ++d_) \
    o[d_] = __builtin_amdgcn_mfma_f32_16x16x32_bf16(pf_, vbuf_[d_], o[d_], 0,0,0); }

__global__ __launch_bounds__(256, 3) void flash_attn(
    const bf16* __restrict__ qkv, const bf16* __restrict__ vT,
    bf16* __restrict__ ctx)
{
  int bh = blockIdx.x;
  int b = bh >> 4, h = bh & 15;
  int tid = threadIdx.x;
  int wave = tid >> 6, lane = tid & 63;
  int quad = lane >> 4, l16 = lane & 15;
  int t = 127 - (blockIdx.y * 4 + wave);   // heavy-first: t=127 dispatched 1st
  int q0 = 16 * t;
  int kmax = q0 + 16;                      // number of causal keys
  int nk = (kmax + 31) >> 5;
  const bf16* Qb = qkv + (size_t)b * SDIM * QKVW + h * 384;
  const bf16* Kb = Qb + 128;
  const bf16* Vb = vT + (size_t)bh * HD * SDIM;
  __shared__ bf16 Ps[4][16][32];

  short8 aq[4];
  #pragma unroll
  for (int c = 0; c < 4; ++c)
    aq[c] = *(const short8*)&Qb[(size_t)(q0 + l16) * QKVW + c * 32 + quad * 8];

  floatx4 o[8];
  #pragma unroll
  for (int d = 0; d < 8; ++d) o[d] = (floatx4)0.0f;
  float m[4] = {-INFINITY, -INFINITY, -INFINITY, -INFINITY};
  float l[4] = {0.0f, 0.0f, 0.0f, 0.0f};

  short8 kb0[8], kb1[8];
  LOAD_K(kb0, 0);
  for (int it = 0; it < nk; it += 2) {
    FLASH_ITER1(it, kb0, kb1);
    if (it + 1 < nk) { FLASH_ITER1(it + 1, kb1, kb0); }
  }

  float rl[4];
  #pragma unroll
  for (int r = 0; r < 4; ++r) rl[r] = 1.0f / l[r];
  #pragma unroll
  for (int d = 0; d < 8; ++d) {
    #pragma unroll
    for (int r = 0; r < 4; ++r) {
      int row = q0 + quad * 4 + r;
      ctx[((size_t)b * SDIM + row) * HID + h * HD + d * 16 + l16] =
          __float2bfloat16(o[d][r] * rl[r]);
    }
  }
}

// ---------------- launcher ----------------
extern "C" void kernel_launch(void* const* d_in, const int* in_sizes, int n_in,
                              void* d_out, int out_size, void* d_ws, size_t ws_size,
                              hipStream_t stream) {
  const float* hidden = (const float*)d_in[0];
  const float* ln1g = (const float*)d_in[1];
  const float* ln1b = (const float*)d_in[2];
  const float* ln2g = (const float*)d_in[3];
  const float* ln2b = (const float*)d_in[4];
  const float* Wqkv = (const float*)d_in[5];
  const float* bqkv = (const float*)d_in[6];
  const float* Wo   = (const float*)d_in[7];
  const float* bo   = (const float*)d_in[8];
  const float* Wfc  = (const float*)d_in[9];
  const float* bfc  = (const float*)d_in[10];
  const float* Wproj= (const float*)d_in[11];
  const float* bproj= (const float*)d_in[12];

  char* ws = (char*)d_ws;
  const size_t SZ_WQKV = (size_t)QKVW * HID * 2;
  const size_t SZ_WO   = (size_t)HID * HID * 2;
  const size_t SZ_WFC  = (size_t)FFD * HID * 2;
  const size_t SZ_WPROJ= (size_t)HID * FFD * 2;
  const size_t SZ_ACT  = (size_t)NTOK * HID * 2;
  const size_t SZ_QKV  = (size_t)NTOK * QKVW * 2;

  bf16* wqkvT = (bf16*)(ws + 0);
  bf16* woT   = (bf16*)(ws + SZ_WQKV);
  bf16* wfcT  = (bf16*)(ws + SZ_WQKV + SZ_WO);
  bf16* wprojT= (bf16*)(ws + SZ_WQKV + SZ_WO + SZ_WFC);
  char* actbase = ws + SZ_WQKV + SZ_WO + SZ_WFC + SZ_WPROJ;
  bf16* xln   = (bf16*)(actbase);
  bf16* mln   = (bf16*)(actbase + SZ_ACT);
  bf16* qkvb  = (bf16*)(actbase + 2 * SZ_ACT);
  bf16* vT    = (bf16*)(actbase + 2 * SZ_ACT + SZ_QKV);
  bf16* ctx   = xln;
  bf16* attnb = wqkvT;
  bf16* hfc   = qkvb;

  dim3 tblk(32, 8);
  transpose_cvt<<<dim3(QKVW / 32, HID / 32), tblk, 0, stream>>>(Wqkv, wqkvT, HID, QKVW);
  transpose_cvt<<<dim3(HID / 32, HID / 32), tblk, 0, stream>>>(Wo, woT, HID, HID);
  transpose_cvt<<<dim3(FFD / 32, HID / 32), tblk, 0, stream>>>(Wfc, wfcT, HID, FFD);
  transpose_cvt<<<dim3(HID / 32, FFD / 32), tblk, 0, stream>>>(Wproj, wprojT, FFD, HID);

  ln_both<<<NTOK, 256, 0, stream>>>(hidden, ln1g, ln1b, ln2g, ln2b, xln, mln);

  // QKV: 128x256/BK=64 2-phase -> (24, 32) = 768 blocks (3 full rounds)
  gemm2p<3, 128><<<dim3(QKVW / 256, NTOK / 128), 512, 0, stream>>>(
      xln, wqkvT, bqkv, nullptr, qkvb, nullptr, nullptr, NTOK, QKVW, HID);

  rope_vt<<<dim3(32, SDIM / 32), 256, 0, stream>>>(qkvb, vT);

  // flash v4: one tile/wave, heavy-first; grid (bh, 128 tiles / 4 waves)
  flash_attn<<<dim3(32, SDIM / 64), 256, 0, stream>>>(qkvb, vT, ctx);

  // Wo: 128x256/BK=64 2-phase -> (8, 32) = 256 blocks (full machine)
  gemm2p<3, 128><<<dim3(HID / 256, NTOK / 128), 512, 0, stream>>>(
      ctx, woT, bo, nullptr, attnb, nullptr, nullptr, NTOK, HID, HID);

  // FC: 256x256/BK=64 2-phase (r5-proven) -> (32, 16) = 512 blocks
  gemm2p<1, 256><<<dim3(FFD / 256, NTOK / 256), 512, 0, stream>>>(
      mln, wfcT, bfc, nullptr, hfc, nullptr, nullptr, NTOK, FFD, HID);

  // proj: 128x256/BK=64 2-phase -> (8, 32) = 256 blocks
  gemm2p<2, 128><<<dim3(HID / 256, NTOK / 128), 512, 0, stream>>>(
      hfc, wprojT, bproj, (float*)d_out, nullptr, attnb, hidden, NTOK, HID, FFD);
}

// Round 8
// 1080.430 us; speedup vs baseline: 1.1728x; 1.1728x over previous
//
#include <hip/hip_runtime.h>
#include <hip/hip_bf16.h>
#include <math.h>

#define BDIM 2
#define SDIM 2048
#define HDIM 16
#define HD 128
#define HID 2048
#define FFD 8192
#define NTOK (BDIM*SDIM)
#define QKVW (3*HID)

typedef __hip_bfloat16 bf16;
typedef __attribute__((ext_vector_type(8))) short short8;
typedef __attribute__((ext_vector_type(4))) short short4_;
typedef __attribute__((ext_vector_type(4))) float floatx4;

__device__ inline short bfbits(float f) {
  bf16 h = __float2bfloat16(f);
  short s;
  __builtin_memcpy(&s, &h, 2);
  return s;
}

// Abramowitz-Stegun 7.1.26 erf approximation, |err| <= 1.5e-7.
__device__ inline float fast_erf(float x) {
  float ax = fabsf(x);
  float t = __builtin_amdgcn_rcpf(1.0f + 0.3275911f * ax);
  float p = t * (0.254829592f + t * (-0.284496736f + t * (1.421413741f
          + t * (-1.453152027f + t * 1.061405429f))));
  float e = __expf(-ax * ax);
  float r = 1.0f - p * e;
  return copysignf(r, x);
}

// ---------------- weight transpose + f32->bf16 convert ----------------
__global__ __launch_bounds__(256) void transpose_cvt(
    const float* __restrict__ W, bf16* __restrict__ Wt, int K, int N)
{
  __shared__ float tile[32][33];
  int n0 = blockIdx.x * 32, k0 = blockIdx.y * 32;
  int tx = threadIdx.x, ty = threadIdx.y;  // 32 x 8
  #pragma unroll
  for (int r = ty; r < 32; r += 8)
    tile[r][tx] = W[(size_t)(k0 + r) * N + n0 + tx];
  __syncthreads();
  #pragma unroll
  for (int r = ty; r < 32; r += 8)
    Wt[(size_t)(n0 + r) * K + k0 + tx] = __float2bfloat16(tile[tx][r]);
}

// ---------------- fused LayerNorm (both LN1 and LN2) ----------------
__global__ __launch_bounds__(256) void ln_both(
    const float* __restrict__ x,
    const float* __restrict__ g1, const float* __restrict__ b1,
    const float* __restrict__ g2, const float* __restrict__ b2,
    bf16* __restrict__ o1, bf16* __restrict__ o2)
{
  int row = blockIdx.x;
  int tid = threadIdx.x;
  const float4* xr = (const float4*)(x + (size_t)row * HID);
  float4 va = xr[tid], vb = xr[tid + 256];
  float s = va.x + va.y + va.z + va.w + vb.x + vb.y + vb.z + vb.w;
  float q = va.x*va.x + va.y*va.y + va.z*va.z + va.w*va.w
          + vb.x*vb.x + vb.y*vb.y + vb.z*vb.z + vb.w*vb.w;
  #pragma unroll
  for (int off = 1; off < 64; off <<= 1) {
    s += __shfl_xor(s, off);
    q += __shfl_xor(q, off);
  }
  __shared__ float red[8];
  int wave = tid >> 6;
  if ((tid & 63) == 0) { red[wave] = s; red[4 + wave] = q; }
  __syncthreads();
  s = red[0] + red[1] + red[2] + red[3];
  q = red[4] + red[5] + red[6] + red[7];
  float mu = s * (1.0f / HID);
  float var = q * (1.0f / HID) - mu * mu;
  float rs = rsqrtf(var + 1e-5f);

  const float4* g1v = (const float4*)g1; const float4* b1v = (const float4*)b1;
  const float4* g2v = (const float4*)g2; const float4* b2v = (const float4*)b2;
  short4_* o1v = (short4_*)(o1 + (size_t)row * HID);
  short4_* o2v = (short4_*)(o2 + (size_t)row * HID);
  #pragma unroll
  for (int p = 0; p < 2; ++p) {
    int e = tid + p * 256;
    float4 xv = (p == 0) ? va : vb;
    float4 gv = g1v[e], bv = b1v[e];
    short4_ pk;
    pk[0] = bfbits((xv.x - mu) * rs * gv.x + bv.x);
    pk[1] = bfbits((xv.y - mu) * rs * gv.y + bv.y);
    pk[2] = bfbits((xv.z - mu) * rs * gv.z + bv.z);
    pk[3] = bfbits((xv.w - mu) * rs * gv.w + bv.w);
    o1v[e] = pk;
    gv = g2v[e]; bv = b2v[e];
    pk[0] = bfbits((xv.x - mu) * rs * gv.x + bv.x);
    pk[1] = bfbits((xv.y - mu) * rs * gv.y + bv.y);
    pk[2] = bfbits((xv.z - mu) * rs * gv.z + bv.z);
    pk[3] = bfbits((xv.w - mu) * rs * gv.w + bv.w);
    o2v[e] = pk;
  }
}

// ---------------- bf16 GEMM: BM x 256 tile, BK=64, 2-phase simple ----------
// r5/r6-verified minimum-T3 recipe (m230): stage-next -> compute-current ->
// ONE __syncthreads per K-tile; no asm pins. XOR chunk swizzle both-sides.
// EPI 1: bf16 out = gelu(acc + bias)   (fast_erf)
// EPI 2: f32 out = acc + bias + (f32)r1b + r2
// EPI 3: bf16 out = acc + bias
template<int EPI, int BM>
__global__ __launch_bounds__(512, 2) void gemm2p(
    const bf16* __restrict__ A, const bf16* __restrict__ Bt,
    const float* __restrict__ bias,
    float* __restrict__ Cf, bf16* __restrict__ Cb,
    const bf16* __restrict__ r1b, const float* __restrict__ r2,
    int M, int N, int K)
{
  constexpr int NI = BM / 32;   // acc row-frags per wave (4 or 8)
  __shared__ bf16 SA[2][BM * 64];
  __shared__ bf16 SB[2][256 * 64];
  const int tid = threadIdx.x;
  const int wave = tid >> 6, lane = tid & 63;
  const int quad = lane >> 4, l16 = lane & 15;
  const int wr = wave >> 2, wc = wave & 3;
  const int n0 = blockIdx.x * 256, m0 = blockIdx.y * BM;

  const int stg_r = tid >> 3;
  const int stg_c = ((tid & 7) ^ ((tid >> 3) & 7)) << 3;  // element offset
  const bf16* stgA = A + (size_t)(m0 + stg_r) * K + stg_c;
  const bf16* stgB = Bt + (size_t)(n0 + stg_r) * K + stg_c;

  floatx4 acc[NI][4];
  #pragma unroll
  for (int i = 0; i < NI; ++i)
    #pragma unroll
    for (int j = 0; j < 4; ++j) acc[i][j] = (floatx4)0.0f;

  const int KT = K >> 6;

#define STAGE_2P(KT1, BUF) {                                                   \
  const bf16* ga_ = stgA + (size_t)(KT1) * 64;                                 \
  const bf16* gb_ = stgB + (size_t)(KT1) * 64;                                 \
  _Pragma("unroll")                                                            \
  for (int s_ = 0; s_ < BM / 64; ++s_)                                         \
    __builtin_amdgcn_global_load_lds(                                          \
        (const __attribute__((address_space(1))) void*)(ga_ + (size_t)s_ * 64 * K), \
        (__attribute__((address_space(3))) void*)&SA[BUF][s_ * 4096 + wave * 512], 16, 0, 0); \
  _Pragma("unroll")                                                            \
  for (int s_ = 0; s_ < 4; ++s_)                                               \
    __builtin_amdgcn_global_load_lds(                                          \
        (const __attribute__((address_space(1))) void*)(gb_ + (size_t)s_ * 64 * K), \
        (__attribute__((address_space(3))) void*)&SB[BUF][s_ * 4096 + wave * 512], 16, 0, 0); }

  STAGE_2P(0, 0);
  __syncthreads();

  for (int kt = 0; kt < KT; ++kt) {
    const int cur = kt & 1;
    if (kt + 1 < KT) STAGE_2P(kt + 1, cur ^ 1);
    const bf16* as_ = &SA[cur][0];
    const bf16* bs_ = &SB[cur][0];
    #pragma unroll
    for (int kc = 0; kc < 2; ++kc) {
      const int csw = (((kc * 4 + quad) ^ (l16 & 7)) << 3);
      short8 av[NI], bv[4];
      #pragma unroll
      for (int i = 0; i < NI; ++i)
        av[i] = *(const short8*)&as_[(wr * (BM / 2) + i * 16 + l16) * 64 + csw];
      #pragma unroll
      for (int j = 0; j < 4; ++j)
        bv[j] = *(const short8*)&bs_[(wc * 64 + j * 16 + l16) * 64 + csw];
      #pragma unroll
      for (int i = 0; i < NI; ++i)
        #pragma unroll
        for (int j = 0; j < 4; ++j)
          acc[i][j] = __builtin_amdgcn_mfma_f32_16x16x32_bf16(av[i], bv[j], acc[i][j], 0, 0, 0);
    }
    __syncthreads();
  }
#undef STAGE_2P

  #pragma unroll
  for (int i = 0; i < NI; ++i) {
    #pragma unroll
    for (int j = 0; j < 4; ++j) {
      int col = n0 + wc * 64 + j * 16 + l16;
      float bsv = bias[col];
      #pragma unroll
      for (int r = 0; r < 4; ++r) {
        int row = m0 + wr * (BM / 2) + i * 16 + quad * 4 + r;
        size_t idx = (size_t)row * N + col;
        float v = acc[i][j][r] + bsv;
        if (EPI == 1) {
          v = 0.5f * v * (1.0f + fast_erf(v * 0.70710678118654752f));
          Cb[idx] = __float2bfloat16(v);
        } else if (EPI == 2) {
          Cf[idx] = v + __bfloat162float(r1b[idx]) + r2[idx];
        } else {
          Cb[idx] = __float2bfloat16(v);
        }
      }
    }
  }
}

// ---------------- RoPE in-place + Q pre-scale + V transpose ----------------
__global__ __launch_bounds__(256) void rope_vt(
    bf16* __restrict__ qkv, bf16* __restrict__ vT)
{
  int bh = blockIdx.x, s0 = blockIdx.y * 32;
  int b = bh >> 4, h = bh & 15;
  int tid = threadIdx.x;
  __shared__ bf16 vs[32][136];
  const float qsc = 0.12751740f;  // (1/sqrt(128)) * log2(e)

  for (int idx = tid; idx < 512; idx += 256) {
    int sl = idx >> 4, d = idx & 15;
    int s = s0 + sl;
    bf16* base = qkv + (size_t)(b * SDIM + s) * QKVW + h * 384;
    float fr = (float)s * expf(-(float)d * 0.5756462732485114f); // ln(10000)/16
    float c = cosf(fr), sn = sinf(fr);
    float q1 = __bfloat162float(base[d]);
    float q2 = __bfloat162float(base[d + 16]);
    float k1 = __bfloat162float(base[128 + d]);
    float k2 = __bfloat162float(base[128 + d + 16]);
    base[d]        = __float2bfloat16(qsc * (q1 * c - q2 * sn));
    base[d + 16]   = __float2bfloat16(qsc * (q2 * c + q1 * sn));
    base[128 + d]      = __float2bfloat16(k1 * c - k2 * sn);
    base[128 + d + 16] = __float2bfloat16(k2 * c + k1 * sn);
  }
  for (int idx = tid; idx < 32 * 96; idx += 256) {
    int sl = idx / 96, d = 32 + idx % 96;
    bf16* base = qkv + (size_t)(b * SDIM + s0 + sl) * QKVW + h * 384;
    base[d] = __float2bfloat16(qsc * __bfloat162float(base[d]));
  }

  for (int idx = tid; idx < 32 * 128; idx += 256) {
    int sl = idx >> 7, d = idx & 127;
    vs[sl][d] = qkv[(size_t)(b * SDIM + s0 + sl) * QKVW + h * 384 + 256 + d];
  }
  __syncthreads();
  for (int idx = tid; idx < 32 * 128; idx += 256) {
    int d = idx >> 5, sl = idx & 31;
    vT[((size_t)bh * HD + d) * SDIM + s0 + sl] = vs[sl][d];
  }
}

// ---------------- flash attention v4b: one q-tile per wave ----------------
// r7 failure analysis: __launch_bounds__(256,3) forced VGPR to 84 -> the
// ~130-reg working set spilled to scratch (WRITE_SIZE 16->304 MB, kernel
// went HBM/scratch-bound, 408 us). v4b: SAME structure, NO min-waves pin —
// compiler allocates what it needs (<=170 -> 3 waves/SIMD naturally, no
// spill). Heavy-first tile mapping retained for tail balance.
#define LOAD_K(KB, K0) { \
  int krow_ = (K0); \
  _Pragma("unroll") for (int nh_ = 0; nh_ < 2; ++nh_) \
    _Pragma("unroll") for (int c_ = 0; c_ < 4; ++c_) \
      KB[nh_*4+c_] = *(const short8*)&Kb[(size_t)(krow_ + nh_*16 + l16) * QKVW + c_*32 + quad*8]; }

#define SOFTMAX1(S0, S1, K0, DOMASK) { \
  if (DOMASK) { \
    _Pragma("unroll") for (int r_ = 0; r_ < 4; ++r_) { \
      int row_ = q0 + quad*4 + r_; \
      S0[r_] = ((K0) + l16 <= row_) ? S0[r_] : -1e30f; \
      S1[r_] = ((K0) + 16 + l16 <= row_) ? S1[r_] : -1e30f; } } \
  _Pragma("unroll") for (int r_ = 0; r_ < 4; ++r_) { \
    float mx_ = fmaxf(S0[r_], S1[r_]); \
    mx_ = fmaxf(mx_, __shfl_xor(mx_, 1)); \
    mx_ = fmaxf(mx_, __shfl_xor(mx_, 2)); \
    mx_ = fmaxf(mx_, __shfl_xor(mx_, 4)); \
    mx_ = fmaxf(mx_, __shfl_xor(mx_, 8)); \
    float mnew_ = fmaxf(m[r_], mx_); \
    float alpha_ = __builtin_amdgcn_exp2f(m[r_] - mnew_); \
    m[r_] = mnew_; \
    S0[r_] = __builtin_amdgcn_exp2f(S0[r_] - mnew_); \
    S1[r_] = __builtin_amdgcn_exp2f(S1[r_] - mnew_); \
    float sm_ = S0[r_] + S1[r_]; \
    sm_ += __shfl_xor(sm_, 1); sm_ += __shfl_xor(sm_, 2); \
    sm_ += __shfl_xor(sm_, 4); sm_ += __shfl_xor(sm_, 8); \
    l[r_] = l[r_] * alpha_ + sm_; \
    _Pragma("unroll") for (int d_ = 0; d_ < 8; ++d_) o[d_][r_] *= alpha_; \
    Ps[wave][quad*4 + r_][l16]      = __float2bfloat16(S0[r_]); \
    Ps[wave][quad*4 + r_][16 + l16] = __float2bfloat16(S1[r_]); } }

#define FLASH_ITER1(IT, KC, KN) { \
  const int k0_ = (IT) * 32; \
  const int k0n_ = ((IT) + 1 < nk) ? k0_ + 32 : 0; \
  LOAD_K(KN, k0n_); \
  short8 vbuf_[8]; \
  _Pragma("unroll") for (int d_ = 0; d_ < 8; ++d_) \
    vbuf_[d_] = *(const short8*)&Vb[(size_t)(d_*16 + l16) * SDIM + k0_ + quad*8]; \
  floatx4 sc_[2]; sc_[0] = (floatx4)0.0f; sc_[1] = (floatx4)0.0f; \
  _Pragma("unroll") for (int c_ = 0; c_ < 4; ++c_) { \
    sc_[0] = __builtin_amdgcn_mfma_f32_16x16x32_bf16(aq[c_], KC[c_],   sc_[0], 0,0,0); \
    sc_[1] = __builtin_amdgcn_mfma_f32_16x16x32_bf16(aq[c_], KC[4+c_], sc_[1], 0,0,0); } \
  SOFTMAX1(sc_[0], sc_[1], k0_, (k0_ + 32 >= kmax)); \
  short8 pf_ = *(const short8*)&Ps[wave][l16][quad*8]; \
  _Pragma("unroll") for (int d_ = 0; d_ < 8; ++d_) \
    o[d_] = __builtin_amdgcn_mfma_f32_16x16x32_bf16(pf_, vbuf_[d_], o[d_], 0,0,0); }

__global__ __launch_bounds__(256) void flash_attn(
    const bf16* __restrict__ qkv, const bf16* __restrict__ vT,
    bf16* __restrict__ ctx)
{
  int bh = blockIdx.x;
  int b = bh >> 4, h = bh & 15;
  int tid = threadIdx.x;
  int wave = tid >> 6, lane = tid & 63;
  int quad = lane >> 4, l16 = lane & 15;
  int t = 127 - (blockIdx.y * 4 + wave);   // heavy-first: t=127 dispatched 1st
  int q0 = 16 * t;
  int kmax = q0 + 16;                      // number of causal keys
  int nk = (kmax + 31) >> 5;
  const bf16* Qb = qkv + (size_t)b * SDIM * QKVW + h * 384;
  const bf16* Kb = Qb + 128;
  const bf16* Vb = vT + (size_t)bh * HD * SDIM;
  __shared__ bf16 Ps[4][16][32];

  short8 aq[4];
  #pragma unroll
  for (int c = 0; c < 4; ++c)
    aq[c] = *(const short8*)&Qb[(size_t)(q0 + l16) * QKVW + c * 32 + quad * 8];

  floatx4 o[8];
  #pragma unroll
  for (int d = 0; d < 8; ++d) o[d] = (floatx4)0.0f;
  float m[4] = {-INFINITY, -INFINITY, -INFINITY, -INFINITY};
  float l[4] = {0.0f, 0.0f, 0.0f, 0.0f};

  short8 kb0[8], kb1[8];
  LOAD_K(kb0, 0);
  for (int it = 0; it < nk; it += 2) {
    FLASH_ITER1(it, kb0, kb1);
    if (it + 1 < nk) { FLASH_ITER1(it + 1, kb1, kb0); }
  }

  float rl[4];
  #pragma unroll
  for (int r = 0; r < 4; ++r) rl[r] = 1.0f / l[r];
  #pragma unroll
  for (int d = 0; d < 8; ++d) {
    #pragma unroll
    for (int r = 0; r < 4; ++r) {
      int row = q0 + quad * 4 + r;
      ctx[((size_t)b * SDIM + row) * HID + h * HD + d * 16 + l16] =
          __float2bfloat16(o[d][r] * rl[r]);
    }
  }
}

// ---------------- launcher ----------------
extern "C" void kernel_launch(void* const* d_in, const int* in_sizes, int n_in,
                              void* d_out, int out_size, void* d_ws, size_t ws_size,
                              hipStream_t stream) {
  const float* hidden = (const float*)d_in[0];
  const float* ln1g = (const float*)d_in[1];
  const float* ln1b = (const float*)d_in[2];
  const float* ln2g = (const float*)d_in[3];
  const float* ln2b = (const float*)d_in[4];
  const float* Wqkv = (const float*)d_in[5];
  const float* bqkv = (const float*)d_in[6];
  const float* Wo   = (const float*)d_in[7];
  const float* bo   = (const float*)d_in[8];
  const float* Wfc  = (const float*)d_in[9];
  const float* bfc  = (const float*)d_in[10];
  const float* Wproj= (const float*)d_in[11];
  const float* bproj= (const float*)d_in[12];

  char* ws = (char*)d_ws;
  const size_t SZ_WQKV = (size_t)QKVW * HID * 2;
  const size_t SZ_WO   = (size_t)HID * HID * 2;
  const size_t SZ_WFC  = (size_t)FFD * HID * 2;
  const size_t SZ_WPROJ= (size_t)HID * FFD * 2;
  const size_t SZ_ACT  = (size_t)NTOK * HID * 2;
  const size_t SZ_QKV  = (size_t)NTOK * QKVW * 2;

  bf16* wqkvT = (bf16*)(ws + 0);
  bf16* woT   = (bf16*)(ws + SZ_WQKV);
  bf16* wfcT  = (bf16*)(ws + SZ_WQKV + SZ_WO);
  bf16* wprojT= (bf16*)(ws + SZ_WQKV + SZ_WO + SZ_WFC);
  char* actbase = ws + SZ_WQKV + SZ_WO + SZ_WFC + SZ_WPROJ;
  bf16* xln   = (bf16*)(actbase);
  bf16* mln   = (bf16*)(actbase + SZ_ACT);
  bf16* qkvb  = (bf16*)(actbase + 2 * SZ_ACT);
  bf16* vT    = (bf16*)(actbase + 2 * SZ_ACT + SZ_QKV);
  bf16* ctx   = xln;
  bf16* attnb = wqkvT;
  bf16* hfc   = qkvb;

  dim3 tblk(32, 8);
  transpose_cvt<<<dim3(QKVW / 32, HID / 32), tblk, 0, stream>>>(Wqkv, wqkvT, HID, QKVW);
  transpose_cvt<<<dim3(HID / 32, HID / 32), tblk, 0, stream>>>(Wo, woT, HID, HID);
  transpose_cvt<<<dim3(FFD / 32, HID / 32), tblk, 0, stream>>>(Wfc, wfcT, HID, FFD);
  transpose_cvt<<<dim3(HID / 32, FFD / 32), tblk, 0, stream>>>(Wproj, wprojT, FFD, HID);

  ln_both<<<NTOK, 256, 0, stream>>>(hidden, ln1g, ln1b, ln2g, ln2b, xln, mln);

  // QKV: 128x256/BK=64 2-phase -> (24, 32) = 768 blocks (3 full rounds)
  gemm2p<3, 128><<<dim3(QKVW / 256, NTOK / 128), 512, 0, stream>>>(
      xln, wqkvT, bqkv, nullptr, qkvb, nullptr, nullptr, NTOK, QKVW, HID);

  rope_vt<<<dim3(32, SDIM / 32), 256, 0, stream>>>(qkvb, vT);

  // flash v4b: one tile/wave, heavy-first, no VGPR pin
  flash_attn<<<dim3(32, SDIM / 64), 256, 0, stream>>>(qkvb, vT, ctx);

  // Wo: 128x256/BK=64 2-phase -> (8, 32) = 256 blocks (full machine)
  gemm2p<3, 128><<<dim3(HID / 256, NTOK / 128), 512, 0, stream>>>(
      ctx, woT, bo, nullptr, attnb, nullptr, nullptr, NTOK, HID, HID);

  // FC: 256x256/BK=64 2-phase (r5-proven) -> (32, 16) = 512 blocks
  gemm2p<1, 256><<<dim3(FFD / 256, NTOK / 256), 512, 0, stream>>>(
      mln, wfcT, bfc, nullptr, hfc, nullptr, nullptr, NTOK, FFD, HID);

  // proj: 128x256/BK=64 2-phase -> (8, 32) = 256 blocks
  gemm2p<2, 128><<<dim3(HID / 256, NTOK / 128), 512, 0, stream>>>(
      hfc, wprojT, bproj, (float*)d_out, nullptr, attnb, hidden, NTOK, HID, FFD);
}

// Round 9
// 1023.000 us; speedup vs baseline: 1.2387x; 1.0561x over previous
//
#include <hip/hip_runtime.h>
#include <hip/hip_bf16.h>
#include <math.h>

#define BDIM 2
#define SDIM 2048
#define HDIM 16
#define HD 128
#define HID 2048
#define FFD 8192
#define NTOK (BDIM*SDIM)
#define QKVW (3*HID)

typedef __hip_bfloat16 bf16;
typedef __attribute__((ext_vector_type(8))) short short8;
typedef __attribute__((ext_vector_type(4))) short short4_;
typedef __attribute__((ext_vector_type(4))) float floatx4;

__device__ inline short bfbits(float f) {
  bf16 h = __float2bfloat16(f);
  short s;
  __builtin_memcpy(&s, &h, 2);
  return s;
}

// Abramowitz-Stegun 7.1.26 erf approximation, |err| <= 1.5e-7.
__device__ inline float fast_erf(float x) {
  float ax = fabsf(x);
  float t = __builtin_amdgcn_rcpf(1.0f + 0.3275911f * ax);
  float p = t * (0.254829592f + t * (-0.284496736f + t * (1.421413741f
          + t * (-1.453152027f + t * 1.061405429f))));
  float e = __expf(-ax * ax);
  float r = 1.0f - p * e;
  return copysignf(r, x);
}

// ---------------- weight transpose + f32->bf16 convert ----------------
__global__ __launch_bounds__(256) void transpose_cvt(
    const float* __restrict__ W, bf16* __restrict__ Wt, int K, int N)
{
  __shared__ float tile[32][33];
  int n0 = blockIdx.x * 32, k0 = blockIdx.y * 32;
  int tx = threadIdx.x, ty = threadIdx.y;  // 32 x 8
  #pragma unroll
  for (int r = ty; r < 32; r += 8)
    tile[r][tx] = W[(size_t)(k0 + r) * N + n0 + tx];
  __syncthreads();
  #pragma unroll
  for (int r = ty; r < 32; r += 8)
    Wt[(size_t)(n0 + r) * K + k0 + tx] = __float2bfloat16(tile[tx][r]);
}

// ---------------- fused LayerNorm (both LN1 and LN2) ----------------
__global__ __launch_bounds__(256) void ln_both(
    const float* __restrict__ x,
    const float* __restrict__ g1, const float* __restrict__ b1,
    const float* __restrict__ g2, const float* __restrict__ b2,
    bf16* __restrict__ o1, bf16* __restrict__ o2)
{
  int row = blockIdx.x;
  int tid = threadIdx.x;
  const float4* xr = (const float4*)(x + (size_t)row * HID);
  float4 va = xr[tid], vb = xr[tid + 256];
  float s = va.x + va.y + va.z + va.w + vb.x + vb.y + vb.z + vb.w;
  float q = va.x*va.x + va.y*va.y + va.z*va.z + va.w*va.w
          + vb.x*vb.x + vb.y*vb.y + vb.z*vb.z + vb.w*vb.w;
  #pragma unroll
  for (int off = 1; off < 64; off <<= 1) {
    s += __shfl_xor(s, off);
    q += __shfl_xor(q, off);
  }
  __shared__ float red[8];
  int wave = tid >> 6;
  if ((tid & 63) == 0) { red[wave] = s; red[4 + wave] = q; }
  __syncthreads();
  s = red[0] + red[1] + red[2] + red[3];
  q = red[4] + red[5] + red[6] + red[7];
  float mu = s * (1.0f / HID);
  float var = q * (1.0f / HID) - mu * mu;
  float rs = rsqrtf(var + 1e-5f);

  const float4* g1v = (const float4*)g1; const float4* b1v = (const float4*)b1;
  const float4* g2v = (const float4*)g2; const float4* b2v = (const float4*)b2;
  short4_* o1v = (short4_*)(o1 + (size_t)row * HID);
  short4_* o2v = (short4_*)(o2 + (size_t)row * HID);
  #pragma unroll
  for (int p = 0; p < 2; ++p) {
    int e = tid + p * 256;
    float4 xv = (p == 0) ? va : vb;
    float4 gv = g1v[e], bv = b1v[e];
    short4_ pk;
    pk[0] = bfbits((xv.x - mu) * rs * gv.x + bv.x);
    pk[1] = bfbits((xv.y - mu) * rs * gv.y + bv.y);
    pk[2] = bfbits((xv.z - mu) * rs * gv.z + bv.z);
    pk[3] = bfbits((xv.w - mu) * rs * gv.w + bv.w);
    o1v[e] = pk;
    gv = g2v[e]; bv = b2v[e];
    pk[0] = bfbits((xv.x - mu) * rs * gv.x + bv.x);
    pk[1] = bfbits((xv.y - mu) * rs * gv.y + bv.y);
    pk[2] = bfbits((xv.z - mu) * rs * gv.z + bv.z);
    pk[3] = bfbits((xv.w - mu) * rs * gv.w + bv.w);
    o2v[e] = pk;
  }
}

// ---------------- bf16 GEMM: BM x 256 tile, BK=64, 2-phase simple ----------
// r5/r6-verified minimum-T3 recipe (m230): stage-next -> compute-current ->
// ONE __syncthreads per K-tile; no asm pins. XOR chunk swizzle both-sides.
// EPI 1: bf16 out = gelu(acc + bias)   (fast_erf)
// EPI 2: f32 out = acc + bias + (f32)r1b + r2
// EPI 3: bf16 out = acc + bias
template<int EPI, int BM>
__global__ __launch_bounds__(512, 2) void gemm2p(
    const bf16* __restrict__ A, const bf16* __restrict__ Bt,
    const float* __restrict__ bias,
    float* __restrict__ Cf, bf16* __restrict__ Cb,
    const bf16* __restrict__ r1b, const float* __restrict__ r2,
    int M, int N, int K)
{
  constexpr int NI = BM / 32;   // acc row-frags per wave (4 or 8)
  __shared__ bf16 SA[2][BM * 64];
  __shared__ bf16 SB[2][256 * 64];
  const int tid = threadIdx.x;
  const int wave = tid >> 6, lane = tid & 63;
  const int quad = lane >> 4, l16 = lane & 15;
  const int wr = wave >> 2, wc = wave & 3;
  const int n0 = blockIdx.x * 256, m0 = blockIdx.y * BM;

  const int stg_r = tid >> 3;
  const int stg_c = ((tid & 7) ^ ((tid >> 3) & 7)) << 3;  // element offset
  const bf16* stgA = A + (size_t)(m0 + stg_r) * K + stg_c;
  const bf16* stgB = Bt + (size_t)(n0 + stg_r) * K + stg_c;

  floatx4 acc[NI][4];
  #pragma unroll
  for (int i = 0; i < NI; ++i)
    #pragma unroll
    for (int j = 0; j < 4; ++j) acc[i][j] = (floatx4)0.0f;

  const int KT = K >> 6;

#define STAGE_2P(KT1, BUF) {                                                   \
  const bf16* ga_ = stgA + (size_t)(KT1) * 64;                                 \
  const bf16* gb_ = stgB + (size_t)(KT1) * 64;                                 \
  _Pragma("unroll")                                                            \
  for (int s_ = 0; s_ < BM / 64; ++s_)                                         \
    __builtin_amdgcn_global_load_lds(                                          \
        (const __attribute__((address_space(1))) void*)(ga_ + (size_t)s_ * 64 * K), \
        (__attribute__((address_space(3))) void*)&SA[BUF][s_ * 4096 + wave * 512], 16, 0, 0); \
  _Pragma("unroll")                                                            \
  for (int s_ = 0; s_ < 4; ++s_)                                               \
    __builtin_amdgcn_global_load_lds(                                          \
        (const __attribute__((address_space(1))) void*)(gb_ + (size_t)s_ * 64 * K), \
        (__attribute__((address_space(3))) void*)&SB[BUF][s_ * 4096 + wave * 512], 16, 0, 0); }

  STAGE_2P(0, 0);
  __syncthreads();

  for (int kt = 0; kt < KT; ++kt) {
    const int cur = kt & 1;
    if (kt + 1 < KT) STAGE_2P(kt + 1, cur ^ 1);
    const bf16* as_ = &SA[cur][0];
    const bf16* bs_ = &SB[cur][0];
    #pragma unroll
    for (int kc = 0; kc < 2; ++kc) {
      const int csw = (((kc * 4 + quad) ^ (l16 & 7)) << 3);
      short8 av[NI], bv[4];
      #pragma unroll
      for (int i = 0; i < NI; ++i)
        av[i] = *(const short8*)&as_[(wr * (BM / 2) + i * 16 + l16) * 64 + csw];
      #pragma unroll
      for (int j = 0; j < 4; ++j)
        bv[j] = *(const short8*)&bs_[(wc * 64 + j * 16 + l16) * 64 + csw];
      #pragma unroll
      for (int i = 0; i < NI; ++i)
        #pragma unroll
        for (int j = 0; j < 4; ++j)
          acc[i][j] = __builtin_amdgcn_mfma_f32_16x16x32_bf16(av[i], bv[j], acc[i][j], 0, 0, 0);
    }
    __syncthreads();
  }
#undef STAGE_2P

  #pragma unroll
  for (int i = 0; i < NI; ++i) {
    #pragma unroll
    for (int j = 0; j < 4; ++j) {
      int col = n0 + wc * 64 + j * 16 + l16;
      float bsv = bias[col];
      #pragma unroll
      for (int r = 0; r < 4; ++r) {
        int row = m0 + wr * (BM / 2) + i * 16 + quad * 4 + r;
        size_t idx = (size_t)row * N + col;
        float v = acc[i][j][r] + bsv;
        if (EPI == 1) {
          v = 0.5f * v * (1.0f + fast_erf(v * 0.70710678118654752f));
          Cb[idx] = __float2bfloat16(v);
        } else if (EPI == 2) {
          Cf[idx] = v + __bfloat162float(r1b[idx]) + r2[idx];
        } else {
          Cb[idx] = __float2bfloat16(v);
        }
      }
    }
  }
}

// ---------------- RoPE in-place + Q pre-scale + V transpose ----------------
__global__ __launch_bounds__(256) void rope_vt(
    bf16* __restrict__ qkv, bf16* __restrict__ vT)
{
  int bh = blockIdx.x, s0 = blockIdx.y * 32;
  int b = bh >> 4, h = bh & 15;
  int tid = threadIdx.x;
  __shared__ bf16 vs[32][136];
  const float qsc = 0.12751740f;  // (1/sqrt(128)) * log2(e)

  for (int idx = tid; idx < 512; idx += 256) {
    int sl = idx >> 4, d = idx & 15;
    int s = s0 + sl;
    bf16* base = qkv + (size_t)(b * SDIM + s) * QKVW + h * 384;
    float fr = (float)s * expf(-(float)d * 0.5756462732485114f); // ln(10000)/16
    float c = cosf(fr), sn = sinf(fr);
    float q1 = __bfloat162float(base[d]);
    float q2 = __bfloat162float(base[d + 16]);
    float k1 = __bfloat162float(base[128 + d]);
    float k2 = __bfloat162float(base[128 + d + 16]);
    base[d]        = __float2bfloat16(qsc * (q1 * c - q2 * sn));
    base[d + 16]   = __float2bfloat16(qsc * (q2 * c + q1 * sn));
    base[128 + d]      = __float2bfloat16(k1 * c - k2 * sn);
    base[128 + d + 16] = __float2bfloat16(k2 * c + k1 * sn);
  }
  for (int idx = tid; idx < 32 * 96; idx += 256) {
    int sl = idx / 96, d = 32 + idx % 96;
    bf16* base = qkv + (size_t)(b * SDIM + s0 + sl) * QKVW + h * 384;
    base[d] = __float2bfloat16(qsc * __bfloat162float(base[d]));
  }

  for (int idx = tid; idx < 32 * 128; idx += 256) {
    int sl = idx >> 7, d = idx & 127;
    vs[sl][d] = qkv[(size_t)(b * SDIM + s0 + sl) * QKVW + h * 384 + 256 + d];
  }
  __syncthreads();
  for (int idx = tid; idx < 32 * 128; idx += 256) {
    int d = idx >> 5, sl = idx & 31;
    vT[((size_t)bh * HD + d) * SDIM + s0 + sl] = vs[sl][d];
  }
}

// ---------------- flash attention v5: paired tiles + MFMA row-sum ---------
// r6 paired structure (222 us, best) with ONE change: the l-sum is computed
// by an extra MFMA against an all-ones B operand instead of 4 dependent
// __shfl_xor rounds per row (~500 serial cycles of DS latency removed per
// softmax). mfma(P_frag, ones) -> D[q-row][*] = sum_k P[q-row][k], same C
// layout as the PV accumulator, so l[r] = l[r]*alpha[r] + lsum[r] reads
// directly from the result regs. Denominator now sums bf16 P — consistent
// with the bf16-P numerator (was f32 P; diff ~1e-3 relative, within tol).
#define LOAD_K(KB, K0) { \
  int krow_ = (K0); \
  _Pragma("unroll") for (int nh_ = 0; nh_ < 2; ++nh_) \
    _Pragma("unroll") for (int c_ = 0; c_ < 4; ++c_) \
      KB[nh_*4+c_] = *(const short8*)&Kb[(size_t)(krow_ + nh_*16 + l16) * QKVW + c_*32 + quad*8]; }

// softmax minus the sum-reduction: computes alpha into ALPH[], rescales O,
// writes bf16 P to Ps. l is updated later from the MFMA row-sum.
#define SOFTMAXA(S0, S1, MR, OO, ROWQ, DOMASK, K0, SLOT, ALPH) { \
  if (DOMASK) { \
    _Pragma("unroll") for (int r_ = 0; r_ < 4; ++r_) { \
      int row_ = (ROWQ) + quad*4 + r_; \
      S0[r_] = ((K0) + l16 <= row_) ? S0[r_] : -1e30f; \
      S1[r_] = ((K0) + 16 + l16 <= row_) ? S1[r_] : -1e30f; } } \
  _Pragma("unroll") for (int r_ = 0; r_ < 4; ++r_) { \
    float mx_ = fmaxf(S0[r_], S1[r_]); \
    mx_ = fmaxf(mx_, __shfl_xor(mx_, 1)); \
    mx_ = fmaxf(mx_, __shfl_xor(mx_, 2)); \
    mx_ = fmaxf(mx_, __shfl_xor(mx_, 4)); \
    mx_ = fmaxf(mx_, __shfl_xor(mx_, 8)); \
    float mnew_ = fmaxf(MR[r_], mx_); \
    ALPH[r_] = __builtin_amdgcn_exp2f(MR[r_] - mnew_); \
    MR[r_] = mnew_; \
    S0[r_] = __builtin_amdgcn_exp2f(S0[r_] - mnew_); \
    S1[r_] = __builtin_amdgcn_exp2f(S1[r_] - mnew_); \
    _Pragma("unroll") for (int d_ = 0; d_ < 8; ++d_) OO[d_][r_] *= ALPH[r_]; \
    Ps[wave][SLOT][quad*4 + r_][l16]      = __float2bfloat16(S0[r_]); \
    Ps[wave][SLOT][quad*4 + r_][16 + l16] = __float2bfloat16(S1[r_]); } }

#define FLASH_ITER(IT, KC, KN) { \
  const int k0_ = (IT) * 32; \
  const int k0n_ = ((IT) + 1 < nk) ? k0_ + 32 : 0; \
  LOAD_K(KN, k0n_); \
  short8 vbuf_[8]; \
  _Pragma("unroll") for (int d_ = 0; d_ < 8; ++d_) \
    vbuf_[d_] = *(const short8*)&Vb[(size_t)(d_*16 + l16) * SDIM + k0_ + quad*8]; \
  floatx4 scB_[2]; scB_[0] = (floatx4)0.0f; scB_[1] = (floatx4)0.0f; \
  _Pragma("unroll") for (int c_ = 0; c_ < 4; ++c_) { \
    scB_[0] = __builtin_amdgcn_mfma_f32_16x16x32_bf16(aqB[c_], KC[c_],   scB_[0], 0,0,0); \
    scB_[1] = __builtin_amdgcn_mfma_f32_16x16x32_bf16(aqB[c_], KC[4+c_], scB_[1], 0,0,0); } \
  const bool actA_ = (k0_ <= qa + 15); \
  floatx4 scA_[2]; scA_[0] = (floatx4)0.0f; scA_[1] = (floatx4)0.0f; \
  if (actA_) { \
    _Pragma("unroll") for (int c_ = 0; c_ < 4; ++c_) { \
      scA_[0] = __builtin_amdgcn_mfma_f32_16x16x32_bf16(aqA[c_], KC[c_],   scA_[0], 0,0,0); \
      scA_[1] = __builtin_amdgcn_mfma_f32_16x16x32_bf16(aqA[c_], KC[4+c_], scA_[1], 0,0,0); } } \
  float alB_[4]; \
  SOFTMAXA(scB_[0], scB_[1], mB, oB, qb, (k0_ + 32 >= kmax), k0_, 0, alB_); \
  if (actA_) { \
    float alA_[4]; \
    SOFTMAXA(scA_[0], scA_[1], mA, oA, qa, (k0_ + 32 > qa + 15), k0_, 1, alA_); \
    short8 pfB_ = *(const short8*)&Ps[wave][0][l16][quad*8]; \
    short8 pfA_ = *(const short8*)&Ps[wave][1][l16][quad*8]; \
    floatx4 lsB_ = __builtin_amdgcn_mfma_f32_16x16x32_bf16(pfB_, ones8, (floatx4)0.0f, 0,0,0); \
    floatx4 lsA_ = __builtin_amdgcn_mfma_f32_16x16x32_bf16(pfA_, ones8, (floatx4)0.0f, 0,0,0); \
    _Pragma("unroll") for (int r_ = 0; r_ < 4; ++r_) { \
      lB[r_] = lB[r_] * alB_[r_] + lsB_[r_]; \
      lA[r_] = lA[r_] * alA_[r_] + lsA_[r_]; } \
    _Pragma("unroll") for (int d_ = 0; d_ < 8; ++d_) { \
      oB[d_] = __builtin_amdgcn_mfma_f32_16x16x32_bf16(pfB_, vbuf_[d_], oB[d_], 0,0,0); \
      oA[d_] = __builtin_amdgcn_mfma_f32_16x16x32_bf16(pfA_, vbuf_[d_], oA[d_], 0,0,0); } \
  } else { \
    short8 pfB_ = *(const short8*)&Ps[wave][0][l16][quad*8]; \
    floatx4 lsB_ = __builtin_amdgcn_mfma_f32_16x16x32_bf16(pfB_, ones8, (floatx4)0.0f, 0,0,0); \
    _Pragma("unroll") for (int r_ = 0; r_ < 4; ++r_) \
      lB[r_] = lB[r_] * alB_[r_] + lsB_[r_]; \
    _Pragma("unroll") for (int d_ = 0; d_ < 8; ++d_) \
      oB[d_] = __builtin_amdgcn_mfma_f32_16x16x32_bf16(pfB_, vbuf_[d_], oB[d_], 0,0,0); } }

__global__ __launch_bounds__(256) void flash_attn(
    const bf16* __restrict__ qkv, const bf16* __restrict__ vT,
    bf16* __restrict__ ctx)
{
  int bh = blockIdx.x;
  int b = bh >> 4, h = bh & 15;
  int tid = threadIdx.x;
  int wave = tid >> 6, lane = tid & 63;
  int quad = lane >> 4, l16 = lane & 15;
  int p = blockIdx.y * 4 + wave;       // 0..63
  int qa = 16 * p;
  int qb = SDIM - 16 * (p + 1);
  int kmax = qb + 16;
  int nk = (kmax + 31) >> 5;
  const bf16* Qb = qkv + (size_t)b * SDIM * QKVW + h * 384;
  const bf16* Kb = Qb + 128;
  const bf16* Vb = vT + (size_t)bh * HD * SDIM;
  __shared__ bf16 Ps[4][2][16][32];

  short8 ones8;
  #pragma unroll
  for (int i = 0; i < 8; ++i) ones8[i] = (short)0x3F80;  // bf16 1.0

  short8 aqA[4], aqB[4];
  #pragma unroll
  for (int c = 0; c < 4; ++c) {
    aqA[c] = *(const short8*)&Qb[(size_t)(qa + l16) * QKVW + c * 32 + quad * 8];
    aqB[c] = *(const short8*)&Qb[(size_t)(qb + l16) * QKVW + c * 32 + quad * 8];
  }

  floatx4 oA[8], oB[8];
  #pragma unroll
  for (int d = 0; d < 8; ++d) { oA[d] = (floatx4)0.0f; oB[d] = (floatx4)0.0f; }
  float mA[4] = {-INFINITY, -INFINITY, -INFINITY, -INFINITY};
  float mB[4] = {-INFINITY, -INFINITY, -INFINITY, -INFINITY};
  float lA[4] = {0.0f, 0.0f, 0.0f, 0.0f};
  float lB[4] = {0.0f, 0.0f, 0.0f, 0.0f};

  short8 kb0[8], kb1[8];
  LOAD_K(kb0, 0);
  for (int it = 0; it < nk; it += 2) {
    FLASH_ITER(it, kb0, kb1);
    if (it + 1 < nk) { FLASH_ITER(it + 1, kb1, kb0); }
  }

  float rlA[4], rlB[4];
  #pragma unroll
  for (int r = 0; r < 4; ++r) { rlA[r] = 1.0f / lA[r]; rlB[r] = 1.0f / lB[r]; }
  #pragma unroll
  for (int d = 0; d < 8; ++d) {
    #pragma unroll
    for (int r = 0; r < 4; ++r) {
      int rowA = qa + quad * 4 + r;
      int rowB = qb + quad * 4 + r;
      ctx[((size_t)b * SDIM + rowA) * HID + h * HD + d * 16 + l16] =
          __float2bfloat16(oA[d][r] * rlA[r]);
      ctx[((size_t)b * SDIM + rowB) * HID + h * HD + d * 16 + l16] =
          __float2bfloat16(oB[d][r] * rlB[r]);
    }
  }
}

// ---------------- launcher ----------------
extern "C" void kernel_launch(void* const* d_in, const int* in_sizes, int n_in,
                              void* d_out, int out_size, void* d_ws, size_t ws_size,
                              hipStream_t stream) {
  const float* hidden = (const float*)d_in[0];
  const float* ln1g = (const float*)d_in[1];
  const float* ln1b = (const float*)d_in[2];
  const float* ln2g = (const float*)d_in[3];
  const float* ln2b = (const float*)d_in[4];
  const float* Wqkv = (const float*)d_in[5];
  const float* bqkv = (const float*)d_in[6];
  const float* Wo   = (const float*)d_in[7];
  const float* bo   = (const float*)d_in[8];
  const float* Wfc  = (const float*)d_in[9];
  const float* bfc  = (const float*)d_in[10];
  const float* Wproj= (const float*)d_in[11];
  const float* bproj= (const float*)d_in[12];

  char* ws = (char*)d_ws;
  const size_t SZ_WQKV = (size_t)QKVW * HID * 2;
  const size_t SZ_WO   = (size_t)HID * HID * 2;
  const size_t SZ_WFC  = (size_t)FFD * HID * 2;
  const size_t SZ_WPROJ= (size_t)HID * FFD * 2;
  const size_t SZ_ACT  = (size_t)NTOK * HID * 2;
  const size_t SZ_QKV  = (size_t)NTOK * QKVW * 2;

  bf16* wqkvT = (bf16*)(ws + 0);
  bf16* woT   = (bf16*)(ws + SZ_WQKV);
  bf16* wfcT  = (bf16*)(ws + SZ_WQKV + SZ_WO);
  bf16* wprojT= (bf16*)(ws + SZ_WQKV + SZ_WO + SZ_WFC);
  char* actbase = ws + SZ_WQKV + SZ_WO + SZ_WFC + SZ_WPROJ;
  bf16* xln   = (bf16*)(actbase);
  bf16* mln   = (bf16*)(actbase + SZ_ACT);
  bf16* qkvb  = (bf16*)(actbase + 2 * SZ_ACT);
  bf16* vT    = (bf16*)(actbase + 2 * SZ_ACT + SZ_QKV);
  bf16* ctx   = xln;
  bf16* attnb = wqkvT;
  bf16* hfc   = qkvb;

  dim3 tblk(32, 8);
  transpose_cvt<<<dim3(QKVW / 32, HID / 32), tblk, 0, stream>>>(Wqkv, wqkvT, HID, QKVW);
  transpose_cvt<<<dim3(HID / 32, HID / 32), tblk, 0, stream>>>(Wo, woT, HID, HID);
  transpose_cvt<<<dim3(FFD / 32, HID / 32), tblk, 0, stream>>>(Wfc, wfcT, HID, FFD);
  transpose_cvt<<<dim3(HID / 32, FFD / 32), tblk, 0, stream>>>(Wproj, wprojT, FFD, HID);

  ln_both<<<NTOK, 256, 0, stream>>>(hidden, ln1g, ln1b, ln2g, ln2b, xln, mln);

  // QKV: 128x256/BK=64 2-phase -> (24, 32) = 768 blocks (3 full rounds)
  gemm2p<3, 128><<<dim3(QKVW / 256, NTOK / 128), 512, 0, stream>>>(
      xln, wqkvT, bqkv, nullptr, qkvb, nullptr, nullptr, NTOK, QKVW, HID);

  rope_vt<<<dim3(32, SDIM / 32), 256, 0, stream>>>(qkvb, vT);

  // flash v5: paired tiles (r6 structure) + MFMA row-sum softmax
  flash_attn<<<dim3(32, SDIM / 128), 256, 0, stream>>>(qkvb, vT, ctx);

  // Wo: 128x256/BK=64 2-phase -> (8, 32) = 256 blocks (full machine)
  gemm2p<3, 128><<<dim3(HID / 256, NTOK / 128), 512, 0, stream>>>(
      ctx, woT, bo, nullptr, attnb, nullptr, nullptr, NTOK, HID, HID);

  // FC: 256x256/BK=64 2-phase (r5-proven) -> (32, 16) = 512 blocks
  gemm2p<1, 256><<<dim3(FFD / 256, NTOK / 256), 512, 0, stream>>>(
      mln, wfcT, bfc, nullptr, hfc, nullptr, nullptr, NTOK, FFD, HID);

  // proj: 128x256/BK=64 2-phase -> (8, 32) = 256 blocks
  gemm2p<2, 128><<<dim3(HID / 256, NTOK / 128), 512, 0, stream>>>(
      hfc, wprojT, bproj, (float*)d_out, nullptr, attnb, hidden, NTOK, HID, FFD);
}

// Round 10
// 1009.149 us; speedup vs baseline: 1.2557x; 1.0137x over previous
//
#include <hip/hip_runtime.h>
#include <hip/hip_bf16.h>
#include <math.h>

#define BDIM 2
#define SDIM 2048
#define HDIM 16
#define HD 128
#define HID 2048
#define FFD 8192
#define NTOK (BDIM*SDIM)
#define QKVW (3*HID)

typedef __hip_bfloat16 bf16;
typedef __attribute__((ext_vector_type(8))) short short8;
typedef __attribute__((ext_vector_type(4))) short short4_;
typedef __attribute__((ext_vector_type(4))) float floatx4;

__device__ inline short bfbits(float f) {
  bf16 h = __float2bfloat16(f);
  short s;
  __builtin_memcpy(&s, &h, 2);
  return s;
}

// Abramowitz-Stegun 7.1.26 erf approximation, |err| <= 1.5e-7.
__device__ inline float fast_erf(float x) {
  float ax = fabsf(x);
  float t = __builtin_amdgcn_rcpf(1.0f + 0.3275911f * ax);
  float p = t * (0.254829592f + t * (-0.284496736f + t * (1.421413741f
          + t * (-1.453152027f + t * 1.061405429f))));
  float e = __expf(-ax * ax);
  float r = 1.0f - p * e;
  return copysignf(r, x);
}

// ---------------- weight transpose + f32->bf16 convert ----------------
__global__ __launch_bounds__(256) void transpose_cvt(
    const float* __restrict__ W, bf16* __restrict__ Wt, int K, int N)
{
  __shared__ float tile[32][33];
  int n0 = blockIdx.x * 32, k0 = blockIdx.y * 32;
  int tx = threadIdx.x, ty = threadIdx.y;  // 32 x 8
  #pragma unroll
  for (int r = ty; r < 32; r += 8)
    tile[r][tx] = W[(size_t)(k0 + r) * N + n0 + tx];
  __syncthreads();
  #pragma unroll
  for (int r = ty; r < 32; r += 8)
    Wt[(size_t)(n0 + r) * K + k0 + tx] = __float2bfloat16(tile[tx][r]);
}

// ---------------- fused LayerNorm (both LN1 and LN2) ----------------
__global__ __launch_bounds__(256) void ln_both(
    const float* __restrict__ x,
    const float* __restrict__ g1, const float* __restrict__ b1,
    const float* __restrict__ g2, const float* __restrict__ b2,
    bf16* __restrict__ o1, bf16* __restrict__ o2)
{
  int row = blockIdx.x;
  int tid = threadIdx.x;
  const float4* xr = (const float4*)(x + (size_t)row * HID);
  float4 va = xr[tid], vb = xr[tid + 256];
  float s = va.x + va.y + va.z + va.w + vb.x + vb.y + vb.z + vb.w;
  float q = va.x*va.x + va.y*va.y + va.z*va.z + va.w*va.w
          + vb.x*vb.x + vb.y*vb.y + vb.z*vb.z + vb.w*vb.w;
  #pragma unroll
  for (int off = 1; off < 64; off <<= 1) {
    s += __shfl_xor(s, off);
    q += __shfl_xor(q, off);
  }
  __shared__ float red[8];
  int wave = tid >> 6;
  if ((tid & 63) == 0) { red[wave] = s; red[4 + wave] = q; }
  __syncthreads();
  s = red[0] + red[1] + red[2] + red[3];
  q = red[4] + red[5] + red[6] + red[7];
  float mu = s * (1.0f / HID);
  float var = q * (1.0f / HID) - mu * mu;
  float rs = rsqrtf(var + 1e-5f);

  const float4* g1v = (const float4*)g1; const float4* b1v = (const float4*)b1;
  const float4* g2v = (const float4*)g2; const float4* b2v = (const float4*)b2;
  short4_* o1v = (short4_*)(o1 + (size_t)row * HID);
  short4_* o2v = (short4_*)(o2 + (size_t)row * HID);
  #pragma unroll
  for (int p = 0; p < 2; ++p) {
    int e = tid + p * 256;
    float4 xv = (p == 0) ? va : vb;
    float4 gv = g1v[e], bv = b1v[e];
    short4_ pk;
    pk[0] = bfbits((xv.x - mu) * rs * gv.x + bv.x);
    pk[1] = bfbits((xv.y - mu) * rs * gv.y + bv.y);
    pk[2] = bfbits((xv.z - mu) * rs * gv.z + bv.z);
    pk[3] = bfbits((xv.w - mu) * rs * gv.w + bv.w);
    o1v[e] = pk;
    gv = g2v[e]; bv = b2v[e];
    pk[0] = bfbits((xv.x - mu) * rs * gv.x + bv.x);
    pk[1] = bfbits((xv.y - mu) * rs * gv.y + bv.y);
    pk[2] = bfbits((xv.z - mu) * rs * gv.z + bv.z);
    pk[3] = bfbits((xv.w - mu) * rs * gv.w + bv.w);
    o2v[e] = pk;
  }
}

// ---------------- bf16 GEMM: BM x 256 tile, BK=64, 2-phase simple ----------
// r5/r6-verified minimum-T3 recipe (m230): stage-next -> compute-current ->
// ONE __syncthreads per K-tile; no asm pins. XOR chunk swizzle both-sides.
// EPI 1: bf16 out = gelu(acc + bias)   (fast_erf)
// EPI 2: f32 out = acc + bias + (f32)r1b + r2
// EPI 3: bf16 out = acc + bias
template<int EPI, int BM>
__global__ __launch_bounds__(512, 2) void gemm2p(
    const bf16* __restrict__ A, const bf16* __restrict__ Bt,
    const float* __restrict__ bias,
    float* __restrict__ Cf, bf16* __restrict__ Cb,
    const bf16* __restrict__ r1b, const float* __restrict__ r2,
    int M, int N, int K)
{
  constexpr int NI = BM / 32;   // acc row-frags per wave (4 or 8)
  __shared__ bf16 SA[2][BM * 64];
  __shared__ bf16 SB[2][256 * 64];
  const int tid = threadIdx.x;
  const int wave = tid >> 6, lane = tid & 63;
  const int quad = lane >> 4, l16 = lane & 15;
  const int wr = wave >> 2, wc = wave & 3;
  const int n0 = blockIdx.x * 256, m0 = blockIdx.y * BM;

  const int stg_r = tid >> 3;
  const int stg_c = ((tid & 7) ^ ((tid >> 3) & 7)) << 3;  // element offset
  const bf16* stgA = A + (size_t)(m0 + stg_r) * K + stg_c;
  const bf16* stgB = Bt + (size_t)(n0 + stg_r) * K + stg_c;

  floatx4 acc[NI][4];
  #pragma unroll
  for (int i = 0; i < NI; ++i)
    #pragma unroll
    for (int j = 0; j < 4; ++j) acc[i][j] = (floatx4)0.0f;

  const int KT = K >> 6;

#define STAGE_2P(KT1, BUF) {                                                   \
  const bf16* ga_ = stgA + (size_t)(KT1) * 64;                                 \
  const bf16* gb_ = stgB + (size_t)(KT1) * 64;                                 \
  _Pragma("unroll")                                                            \
  for (int s_ = 0; s_ < BM / 64; ++s_)                                         \
    __builtin_amdgcn_global_load_lds(                                          \
        (const __attribute__((address_space(1))) void*)(ga_ + (size_t)s_ * 64 * K), \
        (__attribute__((address_space(3))) void*)&SA[BUF][s_ * 4096 + wave * 512], 16, 0, 0); \
  _Pragma("unroll")                                                            \
  for (int s_ = 0; s_ < 4; ++s_)                                               \
    __builtin_amdgcn_global_load_lds(                                          \
        (const __attribute__((address_space(1))) void*)(gb_ + (size_t)s_ * 64 * K), \
        (__attribute__((address_space(3))) void*)&SB[BUF][s_ * 4096 + wave * 512], 16, 0, 0); }

  STAGE_2P(0, 0);
  __syncthreads();

  for (int kt = 0; kt < KT; ++kt) {
    const int cur = kt & 1;
    if (kt + 1 < KT) STAGE_2P(kt + 1, cur ^ 1);
    const bf16* as_ = &SA[cur][0];
    const bf16* bs_ = &SB[cur][0];
    #pragma unroll
    for (int kc = 0; kc < 2; ++kc) {
      const int csw = (((kc * 4 + quad) ^ (l16 & 7)) << 3);
      short8 av[NI], bv[4];
      #pragma unroll
      for (int i = 0; i < NI; ++i)
        av[i] = *(const short8*)&as_[(wr * (BM / 2) + i * 16 + l16) * 64 + csw];
      #pragma unroll
      for (int j = 0; j < 4; ++j)
        bv[j] = *(const short8*)&bs_[(wc * 64 + j * 16 + l16) * 64 + csw];
      #pragma unroll
      for (int i = 0; i < NI; ++i)
        #pragma unroll
        for (int j = 0; j < 4; ++j)
          acc[i][j] = __builtin_amdgcn_mfma_f32_16x16x32_bf16(av[i], bv[j], acc[i][j], 0, 0, 0);
    }
    __syncthreads();
  }
#undef STAGE_2P

  #pragma unroll
  for (int i = 0; i < NI; ++i) {
    #pragma unroll
    for (int j = 0; j < 4; ++j) {
      int col = n0 + wc * 64 + j * 16 + l16;
      float bsv = bias[col];
      #pragma unroll
      for (int r = 0; r < 4; ++r) {
        int row = m0 + wr * (BM / 2) + i * 16 + quad * 4 + r;
        size_t idx = (size_t)row * N + col;
        float v = acc[i][j][r] + bsv;
        if (EPI == 1) {
          v = 0.5f * v * (1.0f + fast_erf(v * 0.70710678118654752f));
          Cb[idx] = __float2bfloat16(v);
        } else if (EPI == 2) {
          Cf[idx] = v + __bfloat162float(r1b[idx]) + r2[idx];
        } else {
          Cb[idx] = __float2bfloat16(v);
        }
      }
    }
  }
}

// ---------------- RoPE in-place + Q pre-scale + V transpose ----------------
__global__ __launch_bounds__(256) void rope_vt(
    bf16* __restrict__ qkv, bf16* __restrict__ vT)
{
  int bh = blockIdx.x, s0 = blockIdx.y * 32;
  int b = bh >> 4, h = bh & 15;
  int tid = threadIdx.x;
  __shared__ bf16 vs[32][136];
  const float qsc = 0.12751740f;  // (1/sqrt(128)) * log2(e)

  for (int idx = tid; idx < 512; idx += 256) {
    int sl = idx >> 4, d = idx & 15;
    int s = s0 + sl;
    bf16* base = qkv + (size_t)(b * SDIM + s) * QKVW + h * 384;
    float fr = (float)s * expf(-(float)d * 0.5756462732485114f); // ln(10000)/16
    float c = cosf(fr), sn = sinf(fr);
    float q1 = __bfloat162float(base[d]);
    float q2 = __bfloat162float(base[d + 16]);
    float k1 = __bfloat162float(base[128 + d]);
    float k2 = __bfloat162float(base[128 + d + 16]);
    base[d]        = __float2bfloat16(qsc * (q1 * c - q2 * sn));
    base[d + 16]   = __float2bfloat16(qsc * (q2 * c + q1 * sn));
    base[128 + d]      = __float2bfloat16(k1 * c - k2 * sn);
    base[128 + d + 16] = __float2bfloat16(k2 * c + k1 * sn);
  }
  for (int idx = tid; idx < 32 * 96; idx += 256) {
    int sl = idx / 96, d = 32 + idx % 96;
    bf16* base = qkv + (size_t)(b * SDIM + s0 + sl) * QKVW + h * 384;
    base[d] = __float2bfloat16(qsc * __bfloat162float(base[d]));
  }

  for (int idx = tid; idx < 32 * 128; idx += 256) {
    int sl = idx >> 7, d = idx & 127;
    vs[sl][d] = qkv[(size_t)(b * SDIM + s0 + sl) * QKVW + h * 384 + 256 + d];
  }
  __syncthreads();
  for (int idx = tid; idx < 32 * 128; idx += 256) {
    int d = idx >> 5, sl = idx & 31;
    vT[((size_t)bh * HD + d) * SDIM + s0 + sl] = vs[sl][d];
  }
}

// ---------------- flash attention v6: score-pipelined (T15) ---------------
// r9 (209 us) + cross-iteration pipelining: scores consumed at iter it were
// ISSUED at iter it-1 — per iter: {load V(it) -> issue QK(it+1) MFMAs (K
// prefetched last iter) -> issue LOAD_K(it+2) -> softmax on sc(it) (VALU
// overlaps QK retire + loads) -> lsum/PV MFMAs (V latency hidden)}. All
// buffers ping-ponged via macro params (static reg names, rule #20).
// Math identical to r9 (MFMA row-sum softmax); only issue order changes.
#define LOAD_K(KB, K0) { \
  int krow_ = (K0); \
  _Pragma("unroll") for (int nh_ = 0; nh_ < 2; ++nh_) \
    _Pragma("unroll") for (int c_ = 0; c_ < 4; ++c_) \
      KB[nh_*4+c_] = *(const short8*)&Kb[(size_t)(krow_ + nh_*16 + l16) * QKVW + c_*32 + quad*8]; }

// QK^T for both paired tiles; SNA only when A-tile active at that k0.
#define QK_TILE(KC, SNA, SNB, ACT) { \
  SNB[0] = (floatx4)0.0f; SNB[1] = (floatx4)0.0f; \
  _Pragma("unroll") for (int c_ = 0; c_ < 4; ++c_) { \
    SNB[0] = __builtin_amdgcn_mfma_f32_16x16x32_bf16(aqB[c_], KC[c_],   SNB[0], 0,0,0); \
    SNB[1] = __builtin_amdgcn_mfma_f32_16x16x32_bf16(aqB[c_], KC[4+c_], SNB[1], 0,0,0); } \
  if (ACT) { \
    SNA[0] = (floatx4)0.0f; SNA[1] = (floatx4)0.0f; \
    _Pragma("unroll") for (int c_ = 0; c_ < 4; ++c_) { \
      SNA[0] = __builtin_amdgcn_mfma_f32_16x16x32_bf16(aqA[c_], KC[c_],   SNA[0], 0,0,0); \
      SNA[1] = __builtin_amdgcn_mfma_f32_16x16x32_bf16(aqA[c_], KC[4+c_], SNA[1], 0,0,0); } } }

// softmax minus sum-reduction (alpha out, O rescale, bf16 P to LDS).
#define SOFTMAXA(S0, S1, MR, OO, ROWQ, DOMASK, K0, SLOT, ALPH) { \
  if (DOMASK) { \
    _Pragma("unroll") for (int r_ = 0; r_ < 4; ++r_) { \
      int row_ = (ROWQ) + quad*4 + r_; \
      S0[r_] = ((K0) + l16 <= row_) ? S0[r_] : -1e30f; \
      S1[r_] = ((K0) + 16 + l16 <= row_) ? S1[r_] : -1e30f; } } \
  _Pragma("unroll") for (int r_ = 0; r_ < 4; ++r_) { \
    float mx_ = fmaxf(S0[r_], S1[r_]); \
    mx_ = fmaxf(mx_, __shfl_xor(mx_, 1)); \
    mx_ = fmaxf(mx_, __shfl_xor(mx_, 2)); \
    mx_ = fmaxf(mx_, __shfl_xor(mx_, 4)); \
    mx_ = fmaxf(mx_, __shfl_xor(mx_, 8)); \
    float mnew_ = fmaxf(MR[r_], mx_); \
    ALPH[r_] = __builtin_amdgcn_exp2f(MR[r_] - mnew_); \
    MR[r_] = mnew_; \
    S0[r_] = __builtin_amdgcn_exp2f(S0[r_] - mnew_); \
    S1[r_] = __builtin_amdgcn_exp2f(S1[r_] - mnew_); \
    _Pragma("unroll") for (int d_ = 0; d_ < 8; ++d_) OO[d_][r_] *= ALPH[r_]; \
    Ps[wave][SLOT][quad*4 + r_][l16]      = __float2bfloat16(S0[r_]); \
    Ps[wave][SLOT][quad*4 + r_][16 + l16] = __float2bfloat16(S1[r_]); } }

// One pipelined iteration: consumes scores SPA/SPB (tile IT), produces
// SNA/SNB (tile IT+1 via KQK), loads K(IT+2) into KLD.
#define PIPE_ITER(IT, KQK, KLD, SPA, SPB, SNA, SNB) { \
  const int k0_ = (IT) * 32; \
  short8 vbuf_[8]; \
  _Pragma("unroll") for (int d_ = 0; d_ < 8; ++d_) \
    vbuf_[d_] = *(const short8*)&Vb[(size_t)(d_*16 + l16) * SDIM + k0_ + quad*8]; \
  if ((IT) + 1 < nk) QK_TILE(KQK, SNA, SNB, (((IT)+1)*32 <= qa + 15)); \
  if ((IT) + 2 < nk) LOAD_K(KLD, ((IT)+2)*32); \
  const bool actA_ = (k0_ <= qa + 15); \
  float alB_[4]; \
  SOFTMAXA(SPB[0], SPB[1], mB, oB, qb, (k0_ + 32 >= kmax), k0_, 0, alB_); \
  if (actA_) { \
    float alA_[4]; \
    SOFTMAXA(SPA[0], SPA[1], mA, oA, qa, (k0_ + 32 > qa + 15), k0_, 1, alA_); \
    short8 pfB_ = *(const short8*)&Ps[wave][0][l16][quad*8]; \
    short8 pfA_ = *(const short8*)&Ps[wave][1][l16][quad*8]; \
    floatx4 lsB_ = __builtin_amdgcn_mfma_f32_16x16x32_bf16(pfB_, ones8, (floatx4)0.0f, 0,0,0); \
    floatx4 lsA_ = __builtin_amdgcn_mfma_f32_16x16x32_bf16(pfA_, ones8, (floatx4)0.0f, 0,0,0); \
    _Pragma("unroll") for (int r_ = 0; r_ < 4; ++r_) { \
      lB[r_] = lB[r_] * alB_[r_] + lsB_[r_]; \
      lA[r_] = lA[r_] * alA_[r_] + lsA_[r_]; } \
    _Pragma("unroll") for (int d_ = 0; d_ < 8; ++d_) { \
      oB[d_] = __builtin_amdgcn_mfma_f32_16x16x32_bf16(pfB_, vbuf_[d_], oB[d_], 0,0,0); \
      oA[d_] = __builtin_amdgcn_mfma_f32_16x16x32_bf16(pfA_, vbuf_[d_], oA[d_], 0,0,0); } \
  } else { \
    short8 pfB_ = *(const short8*)&Ps[wave][0][l16][quad*8]; \
    floatx4 lsB_ = __builtin_amdgcn_mfma_f32_16x16x32_bf16(pfB_, ones8, (floatx4)0.0f, 0,0,0); \
    _Pragma("unroll") for (int r_ = 0; r_ < 4; ++r_) \
      lB[r_] = lB[r_] * alB_[r_] + lsB_[r_]; \
    _Pragma("unroll") for (int d_ = 0; d_ < 8; ++d_) \
      oB[d_] = __builtin_amdgcn_mfma_f32_16x16x32_bf16(pfB_, vbuf_[d_], oB[d_], 0,0,0); } }

__global__ __launch_bounds__(256) void flash_attn(
    const bf16* __restrict__ qkv, const bf16* __restrict__ vT,
    bf16* __restrict__ ctx)
{
  int bh = blockIdx.x;
  int b = bh >> 4, h = bh & 15;
  int tid = threadIdx.x;
  int wave = tid >> 6, lane = tid & 63;
  int quad = lane >> 4, l16 = lane & 15;
  int p = blockIdx.y * 4 + wave;       // 0..63
  int qa = 16 * p;
  int qb = SDIM - 16 * (p + 1);
  int kmax = qb + 16;
  int nk = (kmax + 31) >> 5;           // >= 33 for all p
  const bf16* Qb = qkv + (size_t)b * SDIM * QKVW + h * 384;
  const bf16* Kb = Qb + 128;
  const bf16* Vb = vT + (size_t)bh * HD * SDIM;
  __shared__ bf16 Ps[4][2][16][32];

  short8 ones8;
  #pragma unroll
  for (int i = 0; i < 8; ++i) ones8[i] = (short)0x3F80;  // bf16 1.0

  short8 aqA[4], aqB[4];
  #pragma unroll
  for (int c = 0; c < 4; ++c) {
    aqA[c] = *(const short8*)&Qb[(size_t)(qa + l16) * QKVW + c * 32 + quad * 8];
    aqB[c] = *(const short8*)&Qb[(size_t)(qb + l16) * QKVW + c * 32 + quad * 8];
  }

  floatx4 oA[8], oB[8];
  #pragma unroll
  for (int d = 0; d < 8; ++d) { oA[d] = (floatx4)0.0f; oB[d] = (floatx4)0.0f; }
  float mA[4] = {-INFINITY, -INFINITY, -INFINITY, -INFINITY};
  float mB[4] = {-INFINITY, -INFINITY, -INFINITY, -INFINITY};
  float lA[4] = {0.0f, 0.0f, 0.0f, 0.0f};
  float lB[4] = {0.0f, 0.0f, 0.0f, 0.0f};

  short8 kb0[8], kb1[8];
  floatx4 spA[2], spB[2], snA[2], snB[2];

  // Prologue: K(0) -> QK(0) -> sp; K(1) staged.
  LOAD_K(kb0, 0);
  QK_TILE(kb0, spA, spB, true);        // qa >= 0 so tile A active at k0=0
  LOAD_K(kb1, 32);                      // nk >= 33, always valid

  for (int it = 0; it < nk; it += 2) {
    PIPE_ITER(it, kb1, kb0, spA, spB, snA, snB);
    if (it + 1 < nk) { PIPE_ITER(it + 1, kb0, kb1, snA, snB, spA, spB); }
  }

  float rlA[4], rlB[4];
  #pragma unroll
  for (int r = 0; r < 4; ++r) { rlA[r] = 1.0f / lA[r]; rlB[r] = 1.0f / lB[r]; }
  #pragma unroll
  for (int d = 0; d < 8; ++d) {
    #pragma unroll
    for (int r = 0; r < 4; ++r) {
      int rowA = qa + quad * 4 + r;
      int rowB = qb + quad * 4 + r;
      ctx[((size_t)b * SDIM + rowA) * HID + h * HD + d * 16 + l16] =
          __float2bfloat16(oA[d][r] * rlA[r]);
      ctx[((size_t)b * SDIM + rowB) * HID + h * HD + d * 16 + l16] =
          __float2bfloat16(oB[d][r] * rlB[r]);
    }
  }
}

// ---------------- launcher ----------------
extern "C" void kernel_launch(void* const* d_in, const int* in_sizes, int n_in,
                              void* d_out, int out_size, void* d_ws, size_t ws_size,
                              hipStream_t stream) {
  const float* hidden = (const float*)d_in[0];
  const float* ln1g = (const float*)d_in[1];
  const float* ln1b = (const float*)d_in[2];
  const float* ln2g = (const float*)d_in[3];
  const float* ln2b = (const float*)d_in[4];
  const float* Wqkv = (const float*)d_in[5];
  const float* bqkv = (const float*)d_in[6];
  const float* Wo   = (const float*)d_in[7];
  const float* bo   = (const float*)d_in[8];
  const float* Wfc  = (const float*)d_in[9];
  const float* bfc  = (const float*)d_in[10];
  const float* Wproj= (const float*)d_in[11];
  const float* bproj= (const float*)d_in[12];

  char* ws = (char*)d_ws;
  const size_t SZ_WQKV = (size_t)QKVW * HID * 2;
  const size_t SZ_WO   = (size_t)HID * HID * 2;
  const size_t SZ_WFC  = (size_t)FFD * HID * 2;
  const size_t SZ_WPROJ= (size_t)HID * FFD * 2;
  const size_t SZ_ACT  = (size_t)NTOK * HID * 2;
  const size_t SZ_QKV  = (size_t)NTOK * QKVW * 2;

  bf16* wqkvT = (bf16*)(ws + 0);
  bf16* woT   = (bf16*)(ws + SZ_WQKV);
  bf16* wfcT  = (bf16*)(ws + SZ_WQKV + SZ_WO);
  bf16* wprojT= (bf16*)(ws + SZ_WQKV + SZ_WO + SZ_WFC);
  char* actbase = ws + SZ_WQKV + SZ_WO + SZ_WFC + SZ_WPROJ;
  bf16* xln   = (bf16*)(actbase);
  bf16* mln   = (bf16*)(actbase + SZ_ACT);
  bf16* qkvb  = (bf16*)(actbase + 2 * SZ_ACT);
  bf16* vT    = (bf16*)(actbase + 2 * SZ_ACT + SZ_QKV);
  bf16* ctx   = xln;
  bf16* attnb = wqkvT;
  bf16* hfc   = qkvb;

  dim3 tblk(32, 8);
  transpose_cvt<<<dim3(QKVW / 32, HID / 32), tblk, 0, stream>>>(Wqkv, wqkvT, HID, QKVW);
  transpose_cvt<<<dim3(HID / 32, HID / 32), tblk, 0, stream>>>(Wo, woT, HID, HID);
  transpose_cvt<<<dim3(FFD / 32, HID / 32), tblk, 0, stream>>>(Wfc, wfcT, HID, FFD);
  transpose_cvt<<<dim3(HID / 32, FFD / 32), tblk, 0, stream>>>(Wproj, wprojT, FFD, HID);

  ln_both<<<NTOK, 256, 0, stream>>>(hidden, ln1g, ln1b, ln2g, ln2b, xln, mln);

  // QKV: 128x256/BK=64 2-phase -> (24, 32) = 768 blocks (3 full rounds)
  gemm2p<3, 128><<<dim3(QKVW / 256, NTOK / 128), 512, 0, stream>>>(
      xln, wqkvT, bqkv, nullptr, qkvb, nullptr, nullptr, NTOK, QKVW, HID);

  rope_vt<<<dim3(32, SDIM / 32), 256, 0, stream>>>(qkvb, vT);

  // flash v6: paired tiles + MFMA row-sum + score pipelining
  flash_attn<<<dim3(32, SDIM / 128), 256, 0, stream>>>(qkvb, vT, ctx);

  // Wo: 128x256/BK=64 2-phase -> (8, 32) = 256 blocks (full machine)
  gemm2p<3, 128><<<dim3(HID / 256, NTOK / 128), 512, 0, stream>>>(
      ctx, woT, bo, nullptr, attnb, nullptr, nullptr, NTOK, HID, HID);

  // FC: 256x256/BK=64 2-phase (r5-proven) -> (32, 16) = 512 blocks
  gemm2p<1, 256><<<dim3(FFD / 256, NTOK / 256), 512, 0, stream>>>(
      mln, wfcT, bfc, nullptr, hfc, nullptr, nullptr, NTOK, FFD, HID);

  // proj: 128x256/BK=64 2-phase -> (8, 32) = 256 blocks
  gemm2p<2, 128><<<dim3(HID / 256, NTOK / 128), 512, 0, stream>>>(
      hfc, wprojT, bproj, (float*)d_out, nullptr, attnb, hidden, NTOK, HID, FFD);
}